// Round 5
// baseline (599.051 us; speedup 1.0000x reference)
//
#include <hip/hip_runtime.h>
#include <hip/hip_bf16.h>
#include <math.h>

#define HIDDEN 2048
#define NH 16
#define HD 128
#define NB 2
#define SEQ 2048
#define K_DIM 2048

typedef unsigned int u32;
typedef unsigned short ushort_t;
typedef __bf16 bf16x8 __attribute__((ext_vector_type(8)));
typedef float f32x4 __attribute__((ext_vector_type(4)));
typedef ushort_t u16x8 __attribute__((ext_vector_type(8)));

// ---------- fp32 -> (bf16 hi, bf16 lo) split, RNE both halves ----------
__device__ __forceinline__ void split1(float x, unsigned short& h, unsigned short& l) {
    u32 u = __float_as_uint(x);
    u32 hr = (u + 0x7FFFu + ((u >> 16) & 1u)) >> 16;
    h = (unsigned short)hr;
    float r = x - __uint_as_float(hr << 16);
    u32 u2 = __float_as_uint(r);
    l = (unsigned short)((u2 + 0x7FFFu + ((u2 >> 16) & 1u)) >> 16);
}

__device__ __forceinline__ ushort_t bf16r(float x) {
    u32 u = __float_as_uint(x);
    return (ushort_t)((u + 0x7FFFu + ((u >> 16) & 1u)) >> 16);
}

__device__ __forceinline__ void gl_lds16(const void* g, void* l) {
    __builtin_amdgcn_global_load_lds(
        (const __attribute__((address_space(1))) u32*)g,
        (__attribute__((address_space(3))) u32*)l, 16, 0, 0);
}

// ==================== RoPE tables (double-precision trig) ====================
__global__ void k_rope_tables(float* __restrict__ ct, float* __restrict__ st) {
    int idx = blockIdx.x * 256 + threadIdx.x;   // exactly SEQ*64 threads
    int s = idx >> 6, d = idx & 63;
    double inv = pow(10000.0, -(double)d * (1.0 / 64.0));
    double ang = (double)s * inv;
    ct[idx] = (float)cos(ang);
    st[idx] = (float)sin(ang);
}

// ==================== fused fp32 -> bf16 (hi only) for X, Wq, Wk, Wv ========
#define XG 2097152   // X float4 groups
#define WG 1048576   // W float4 groups
__global__ void k_cvt_all(const float4* __restrict__ X, const float4* __restrict__ W0,
                          const float4* __restrict__ W1, const float4* __restrict__ W2,
                          ushort4* __restrict__ Xh, ushort4* __restrict__ H0,
                          ushort4* __restrict__ H1, ushort4* __restrict__ H2) {
    int idx = blockIdx.x * 256 + threadIdx.x;   // XG + 3*WG threads
    const float4* src;
    ushort4* dst;
    int off;
    if (idx < XG) { src = X; dst = Xh; off = idx; }
    else {
        int t = idx - XG;
        int m = t >> 20;        // WG = 2^20
        off = t & (WG - 1);
        src = (m == 0) ? W0 : (m == 1) ? W1 : W2;
        dst = (m == 0) ? H0 : (m == 1) ? H1 : H2;
    }
    float4 x = src[off];
    ushort4 h;
    h.x = bf16r(x.x); h.y = bf16r(x.y); h.z = bf16r(x.z); h.w = bf16r(x.w);
    dst[off] = h;
}

// ==================== fp32 -> bf16 hi/lo split (Wo only) =====================
__global__ void k_split(const float4* __restrict__ src, ushort4* __restrict__ hi,
                        ushort4* __restrict__ lo) {
    int idx = blockIdx.x * 256 + threadIdx.x;
    float4 x = src[idx];
    ushort4 h, l;
    split1(x.x, h.x, l.x);
    split1(x.y, h.y, l.y);
    split1(x.z, h.z, l.z);
    split1(x.w, h.w, l.w);
    hi[idx] = h;
    lo[idx] = l;
}

// ==================== fused QKV plain-bf16 MFMA GEMM =========================
__global__ __launch_bounds__(256)
void k_gemm_qkv(const ushort_t* __restrict__ Xh,
                const ushort_t* __restrict__ W0, const ushort_t* __restrict__ W1,
                const ushort_t* __restrict__ W2,
                const float* __restrict__ b0, const float* __restrict__ b1,
                const float* __restrict__ b2,
                float* __restrict__ o0, float* __restrict__ o1, float* __restrict__ o2) {
    __shared__ ushort_t As[128 * 32];
    __shared__ ushort_t Bs[128 * 32];
    const int tid = threadIdx.x;
    const int lane = tid & 63;
    const int w = tid >> 6;
    const int wm = w & 1, wn = w >> 1;
    const int quad = lane >> 4;
    const int l15 = lane & 15;
    const int m0 = blockIdx.x << 7;
    const int mat = blockIdx.y >> 4;
    const int n0 = (blockIdx.y & 15) << 7;
    const ushort_t* Wsel = (mat == 0) ? W0 : (mat == 1) ? W1 : W2;
    const float* bias = (mat == 0) ? b0 : (mat == 1) ? b1 : b2;
    float* out = (mat == 0) ? o0 : (mat == 1) ? o1 : o2;

    const ushort_t* src = (w < 2) ? Xh : Wsel;
    const int rbase = ((w < 2) ? m0 : n0) + (w & 1) * 64;
    ushort_t* lbase = ((w < 2) ? As : Bs) + (w & 1) * 64 * 32;
    const int lrow = lane >> 2;
    const int lk = (lane & 3) << 3;
    const ushort_t* gp[4];
    ushort_t* lp[4];
#pragma unroll
    for (int i = 0; i < 4; i++) {
        gp[i] = src + (size_t)(rbase + i * 16 + lrow) * K_DIM + lk;
        lp[i] = lbase + i * 512;
    }

    f32x4 acc[4][4];
#pragma unroll
    for (int i = 0; i < 4; i++)
#pragma unroll
        for (int j = 0; j < 4; j++) acc[i][j] = (f32x4){0.f, 0.f, 0.f, 0.f};

    const int aoff = (wm * 64 + l15) * 32 + quad * 8;
    const int boff = (wn * 64 + l15) * 32 + quad * 8;

#pragma unroll
    for (int i = 0; i < 4; i++) gl_lds16(gp[i], lp[i]);
    __syncthreads();
    bf16x8 ah[4], bh[4];
#pragma unroll
    for (int f = 0; f < 4; f++) {
        ah[f] = *(const bf16x8*)&As[aoff + f * 512];
        bh[f] = *(const bf16x8*)&Bs[boff + f * 512];
    }

    for (int kt = 32; kt <= K_DIM; kt += 32) {
        __syncthreads();
        if (kt < K_DIM) {
#pragma unroll
            for (int i = 0; i < 4; i++) gl_lds16(gp[i] + kt, lp[i]);
        }
#pragma unroll
        for (int fm = 0; fm < 4; fm++)
#pragma unroll
            for (int fn = 0; fn < 4; fn++)
                acc[fm][fn] = __builtin_amdgcn_mfma_f32_16x16x32_bf16(ah[fm], bh[fn], acc[fm][fn], 0, 0, 0);
        if (kt < K_DIM) {
            __syncthreads();
#pragma unroll
            for (int f = 0; f < 4; f++) {
                ah[f] = *(const bf16x8*)&As[aoff + f * 512];
                bh[f] = *(const bf16x8*)&Bs[boff + f * 512];
            }
        }
    }

    float bcolv[4];
#pragma unroll
    for (int fn = 0; fn < 4; fn++) bcolv[fn] = bias[n0 + wn * 64 + fn * 16 + l15];

    const int h = n0 >> 7;
    const int bb = m0 >> 11;
    const int sb = (m0 & (SEQ - 1)) + wm * 64 + quad * 4;
    const int d = wn * 64 + l15;
    float* obase = out + ((size_t)(bb * NH + h) * SEQ) * HD;
#pragma unroll
    for (int fm = 0; fm < 4; fm++)
#pragma unroll
        for (int fn = 0; fn < 4; fn++)
#pragma unroll
            for (int r = 0; r < 4; r++)
                obase[(size_t)(sb + fm * 16 + r) * HD + d + fn * 16] =
                    acc[fm][fn][r] + bcolv[fn];
}

// ==================== bf16x3 MFMA GEMM (O-projection) ========================
// A (ctx hi/lo) is in BLOCKED layout (B,NH,S,HD): k-offset within a row is
// (kt>>7)*SEQ*HD + (kt&127). B (Wo hi/lo) is row-major K-contiguous.
__global__ __launch_bounds__(256)
void k_gemm_o(const ushort_t* __restrict__ Ah, const ushort_t* __restrict__ Al,
              const ushort_t* __restrict__ Bh, const ushort_t* __restrict__ Bl,
              const float* __restrict__ bias, float* __restrict__ out) {
    __shared__ ushort_t lds[4][128 * 32];
    const int tid = threadIdx.x;
    const int lane = tid & 63;
    const int w = tid >> 6;
    const int wm = w & 1, wn = w >> 1;
    const int quad = lane >> 4;
    const int l15 = lane & 15;
    const int m0 = blockIdx.x << 7;
    const int n0 = blockIdx.y << 7;
    const bool isA = (w < 2);

    const ushort_t* src = (w == 0) ? Ah : (w == 1) ? Al : (w == 2) ? Bh : Bl;
    const int lrow = lane >> 2;
    const int lk = (lane & 3) << 3;
    const ushort_t* gp[8];
    ushort_t* lp[8];
#pragma unroll
    for (int i = 0; i < 8; i++) {
        if (isA) {
            int m = m0 + i * 16 + lrow;
            int bb = m >> 11, s = m & (SEQ - 1);
            gp[i] = src + ((size_t)bb * NH * SEQ + s) * HD + lk;
        } else {
            gp[i] = src + (size_t)(n0 + i * 16 + lrow) * K_DIM + lk;
        }
        lp[i] = &lds[w][i * 512];
    }

    f32x4 acc[4][4];
#pragma unroll
    for (int i = 0; i < 4; i++)
#pragma unroll
        for (int j = 0; j < 4; j++) acc[i][j] = (f32x4){0.f, 0.f, 0.f, 0.f};

    const int aoff = (wm * 64 + l15) * 32 + quad * 8;
    const int boff = (wn * 64 + l15) * 32 + quad * 8;

#pragma unroll
    for (int i = 0; i < 8; i++) gl_lds16(gp[i], lp[i]);
    __syncthreads();
    bf16x8 ah[4], al[4], bh[4], bl[4];
#pragma unroll
    for (int f = 0; f < 4; f++) {
        ah[f] = *(const bf16x8*)&lds[0][aoff + f * 512];
        al[f] = *(const bf16x8*)&lds[1][aoff + f * 512];
        bh[f] = *(const bf16x8*)&lds[2][boff + f * 512];
        bl[f] = *(const bf16x8*)&lds[3][boff + f * 512];
    }

    for (int kt = 32; kt <= K_DIM; kt += 32) {
        __syncthreads();
        if (kt < K_DIM) {
            const size_t koff = isA ? ((size_t)(kt >> 7) * (SEQ * HD) + (kt & 127)) : (size_t)kt;
#pragma unroll
            for (int i = 0; i < 8; i++) gl_lds16(gp[i] + koff, lp[i]);
        }
#pragma unroll
        for (int fm = 0; fm < 4; fm++)
#pragma unroll
            for (int fn = 0; fn < 4; fn++) {
                acc[fm][fn] = __builtin_amdgcn_mfma_f32_16x16x32_bf16(ah[fm], bh[fn], acc[fm][fn], 0, 0, 0);
                acc[fm][fn] = __builtin_amdgcn_mfma_f32_16x16x32_bf16(ah[fm], bl[fn], acc[fm][fn], 0, 0, 0);
                acc[fm][fn] = __builtin_amdgcn_mfma_f32_16x16x32_bf16(al[fm], bh[fn], acc[fm][fn], 0, 0, 0);
            }
        if (kt < K_DIM) {
            __syncthreads();
#pragma unroll
            for (int f = 0; f < 4; f++) {
                ah[f] = *(const bf16x8*)&lds[0][aoff + f * 512];
                al[f] = *(const bf16x8*)&lds[1][aoff + f * 512];
                bh[f] = *(const bf16x8*)&lds[2][boff + f * 512];
                bl[f] = *(const bf16x8*)&lds[3][boff + f * 512];
            }
        }
    }

    float bcolv[4];
#pragma unroll
    for (int fn = 0; fn < 4; fn++) bcolv[fn] = bias[n0 + wn * 64 + fn * 16 + l15];

    const int mb = m0 + wm * 64 + quad * 4;
    const int nb = n0 + wn * 64 + l15;
#pragma unroll
    for (int fm = 0; fm < 4; fm++)
#pragma unroll
        for (int fn = 0; fn < 4; fn++)
#pragma unroll
            for (int r = 0; r < 4; r++)
                out[(size_t)(mb + fm * 16 + r) * HIDDEN + nb + fn * 16] =
                    acc[fm][fn][r] + bcolv[fn];
}

// ==================== RoPE + pack to bf16 (Q scaled by 1/sqrt(HD)) ===========
__global__ void k_rope_pack(const float* __restrict__ q, const float* __restrict__ k,
                            const float* __restrict__ ct, const float* __restrict__ st,
                            ushort_t* __restrict__ Qb, ushort_t* __restrict__ Kb) {
    int idx = blockIdx.x * 256 + threadIdx.x;   // exactly NB*NH*SEQ*64 threads
    int d = idx & 63;
    int s = (idx >> 6) & (SEQ - 1);
    int bh = idx >> 17;
    size_t base = ((size_t)bh * SEQ + s) * HD;
    float c = ct[(s << 6) + d], sn = st[(s << 6) + d];
    const float scq = 0.08838834764831845f;
    float q0 = q[base + d], q1 = q[base + d + 64];
    Qb[base + d]      = bf16r((q0 * c - q1 * sn) * scq);
    Qb[base + d + 64] = bf16r((q1 * c + q0 * sn) * scq);
    float k0 = k[base + d], k1 = k[base + d + 64];
    Kb[base + d]      = bf16r(k0 * c - k1 * sn);
    Kb[base + d + 64] = bf16r(k1 * c + k0 * sn);
}

// ==================== V transpose + pack: (B,H,S,D) fp32 -> (B,H,D,S) bf16 ===
__global__ __launch_bounds__(256)
void k_vpack(const float* __restrict__ v, ushort_t* __restrict__ vt) {
    __shared__ float t[64][65];
    const int tid = threadIdx.x;
    const int bh = blockIdx.z;
    const int s0 = blockIdx.x << 6;
    const int d0 = blockIdx.y << 6;
    const float* src = v + ((size_t)bh * SEQ + s0) * HD + d0;
    const int rr = tid >> 4;
    const int cc = (tid & 15) << 2;
#pragma unroll
    for (int i = 0; i < 4; i++) {
        float4 x = *(const float4*)(src + (size_t)(i * 16 + rr) * HD + cc);
        t[i * 16 + rr][cc] = x.x;
        t[i * 16 + rr][cc + 1] = x.y;
        t[i * 16 + rr][cc + 2] = x.z;
        t[i * 16 + rr][cc + 3] = x.w;
    }
    __syncthreads();
    const int dr = tid >> 2;
    const int sc_ = (tid & 3) << 4;
    ushort_t* dst = vt + ((size_t)bh * HD + d0 + dr) * SEQ + s0 + sc_;
    u16x8 o0, o1;
#pragma unroll
    for (int u = 0; u < 8; u++) o0[u] = bf16r(t[sc_ + u][dr]);
#pragma unroll
    for (int u = 0; u < 8; u++) o1[u] = bf16r(t[sc_ + 8 + u][dr]);
    *(u16x8*)dst = o0;
    *(u16x8*)(dst + 8) = o1;
}

// ==================== MFMA flash attention v3 ================================
// 256 q-rows/block, 4 waves (64 q-rows each), K-chunks of 128, 1 block/CU.
// Grid: 256 blocks, bh = idx&31 (XCD swizzle: same-head blocks share an XCD's
// L2), qt = idx>>5. Transposed scores (K·Q^T) + transposed PV (V^T·P^T).
// No online max (|score| small). Epilogue re-layouts acc through Ps (LDS) for
// fully-coalesced 16B stores; ctx is written in BLOCKED (B,NH,S,HD) layout.
__global__ __launch_bounds__(256, 1)
void k_flash_mfma(const ushort_t* __restrict__ Qb, const ushort_t* __restrict__ Kb,
                  const ushort_t* __restrict__ Vt,
                  ushort_t* __restrict__ ch, ushort_t* __restrict__ cl) {
    __shared__ ushort_t KV[128 * 136];   // 34.8 KB: K then V chunk
    __shared__ ushort_t Ps[256 * 136];   // 69.6 KB: P (A-layout), then epilogue
    const int tid = threadIdx.x;
    const int lane = tid & 63;
    const int w = tid >> 6;
    const int quad = lane >> 4;
    const int l15 = lane & 15;
    const int bi = blockIdx.x;
    const int bh = bi & 31;              // XCD-swizzle: bh%8 == XCD id
    const int qt = bi >> 5;              // 0..7 (256 q rows each)
    const ushort_t* Qg = Qb + ((size_t)bh * SEQ + ((size_t)qt << 8)) * HD;
    const ushort_t* Kg = Kb + (size_t)bh * SEQ * HD;
    const ushort_t* Vg = Vt + (size_t)bh * HD * SEQ;

    // persistent Q fragments (B-operand): 64 q rows per wave
    bf16x8 qf[4][4];
#pragma unroll
    for (int qi = 0; qi < 4; qi++)
#pragma unroll
        for (int ks = 0; ks < 4; ks++)
            qf[qi][ks] = *(const bf16x8*)(Qg + (size_t)(w * 64 + qi * 16 + l15) * HD + ks * 32 + quad * 8);

    const int sr = tid >> 4;             // staging row 0..15
    const int sc8 = (tid & 15) << 3;     // staging col (8 elems = 16B)

    // prefetch chunk 0 K and V^T into registers
    u16x8 Kreg[8], Vreg[8];
#pragma unroll
    for (int i = 0; i < 8; i++)
        Kreg[i] = *(const u16x8*)(Kg + (size_t)(i * 16 + sr) * HD + sc8);
#pragma unroll
    for (int i = 0; i < 8; i++)
        Vreg[i] = *(const u16x8*)(Vg + (size_t)(i * 16 + sr) * SEQ + sc8);

    f32x4 acc[4][8];
#pragma unroll
    for (int qi = 0; qi < 4; qi++)
#pragma unroll
        for (int d = 0; d < 8; d++) acc[qi][d] = (f32x4){0.f, 0.f, 0.f, 0.f};
    float lsum[4] = {0.f, 0.f, 0.f, 0.f};

    for (int kt = 0; kt < SEQ; kt += 128) {
        const int np = kt + 128;
        __syncthreads();                 // prev chunk's PV reads done
#pragma unroll
        for (int i = 0; i < 8; i++)      // stage K_i; refill Kreg = K_{i+1}
            *(u16x8*)&KV[(i * 16 + sr) * 136 + sc8] = Kreg[i];
        if (np < SEQ) {
#pragma unroll
            for (int i = 0; i < 8; i++)
                Kreg[i] = *(const u16x8*)(Kg + (size_t)(np + i * 16 + sr) * HD + sc8);
        }
        __syncthreads();

        // ---- scores transposed: sc[qi][j] = K(16 rows) x Q(16 rows)^T ----
        f32x4 sc[4][8];
#pragma unroll
        for (int qi = 0; qi < 4; qi++)
#pragma unroll
            for (int j = 0; j < 8; j++) sc[qi][j] = (f32x4){0.f, 0.f, 0.f, 0.f};
#pragma unroll
        for (int ks = 0; ks < 4; ks++) {
            bf16x8 kf[8];
#pragma unroll
            for (int j = 0; j < 8; j++)
                kf[j] = *(const bf16x8*)&KV[(j * 16 + l15) * 136 + ks * 32 + quad * 8];
#pragma unroll
            for (int qi = 0; qi < 4; qi++)
#pragma unroll
                for (int j = 0; j < 8; j++)
                    sc[qi][j] = __builtin_amdgcn_mfma_f32_16x16x32_bf16(
                        kf[j], qf[qi][ks], sc[qi][j], 0, 0, 0);
        }

        // ---- p = exp(score); accumulate l; write P (8B contiguous) ----
#pragma unroll
        for (int qi = 0; qi < 4; qi++) {
            const int prow = (w * 64 + qi * 16 + l15) * 136 + quad * 4;
#pragma unroll
            for (int j = 0; j < 8; j++) {
                float p0 = __expf(sc[qi][j][0]);
                float p1 = __expf(sc[qi][j][1]);
                float p2 = __expf(sc[qi][j][2]);
                float p3 = __expf(sc[qi][j][3]);
                lsum[qi] += (p0 + p1) + (p2 + p3);
                __hip_bfloat162 lo2 = __float22bfloat162_rn({p0, p1});
                __hip_bfloat162 hi2 = __float22bfloat162_rn({p2, p3});
                uint2 pk = make_uint2(*(u32*)&lo2, *(u32*)&hi2);
                *(uint2*)&Ps[prow + j * 16] = pk;
            }
        }
        __syncthreads();                 // kf reads done + Ps visible
#pragma unroll
        for (int i = 0; i < 8; i++)      // stage V_i; refill Vreg = V_{i+1}
            *(u16x8*)&KV[(i * 16 + sr) * 136 + sc8] = Vreg[i];
        if (np < SEQ) {
#pragma unroll
            for (int i = 0; i < 8; i++)
                Vreg[i] = *(const u16x8*)(Vg + (size_t)(i * 16 + sr) * SEQ + np + sc8);
        }
        __syncthreads();

        // ---- PV transposed: acc[qi][db] = V^T(16 d-rows) x P^T ----
#pragma unroll
        for (int ks = 0; ks < 4; ks++) {
            bf16x8 pf[4];
#pragma unroll
            for (int qi = 0; qi < 4; qi++)
                pf[qi] = *(const bf16x8*)&Ps[(w * 64 + qi * 16 + l15) * 136 + ks * 32 + quad * 8];
#pragma unroll
            for (int db = 0; db < 8; db++) {
                bf16x8 vf = *(const bf16x8*)&KV[(db * 16 + l15) * 136 + ks * 32 + quad * 8];
#pragma unroll
                for (int qi = 0; qi < 4; qi++)
                    acc[qi][db] = __builtin_amdgcn_mfma_f32_16x16x32_bf16(vf, pf[qi], acc[qi][db], 0, 0, 0);
            }
        }
    }

    // ---- epilogue: reduce l across quads, normalize, re-layout via LDS ----
    float inv[4];
#pragma unroll
    for (int qi = 0; qi < 4; qi++) {
        float l = lsum[qi];
        l += __shfl_xor(l, 16);
        l += __shfl_xor(l, 32);
        inv[qi] = 1.0f / l;
    }
    const size_t obase = ((size_t)bh * SEQ + ((size_t)qt << 8)) * HD;

    __syncthreads();                     // final PV pf reads done
    // hi pass: acc -> Ps rows (q-local), cols d; then coalesced 16B stores
#pragma unroll
    for (int qi = 0; qi < 4; qi++)
#pragma unroll
        for (int db = 0; db < 8; db++) {
            ushort4 hh;
            ushort_t dum;
            split1(acc[qi][db][0] * inv[qi], hh.x, dum);
            split1(acc[qi][db][1] * inv[qi], hh.y, dum);
            split1(acc[qi][db][2] * inv[qi], hh.z, dum);
            split1(acc[qi][db][3] * inv[qi], hh.w, dum);
            *(ushort4*)&Ps[(w * 64 + qi * 16 + l15) * 136 + db * 16 + quad * 4] = hh;
        }
    __syncthreads();
#pragma unroll
    for (int t = 0; t < 16; t++) {
        int c = t * 256 + tid;
        int row = c >> 4, col8 = (c & 15) << 3;
        *(u16x8*)&ch[obase + (size_t)row * HD + col8] = *(const u16x8*)&Ps[row * 136 + col8];
    }
    __syncthreads();
    // lo pass
#pragma unroll
    for (int qi = 0; qi < 4; qi++)
#pragma unroll
        for (int db = 0; db < 8; db++) {
            ushort4 ll;
            ushort_t dum;
            split1(acc[qi][db][0] * inv[qi], dum, ll.x);
            split1(acc[qi][db][1] * inv[qi], dum, ll.y);
            split1(acc[qi][db][2] * inv[qi], dum, ll.z);
            split1(acc[qi][db][3] * inv[qi], dum, ll.w);
            *(ushort4*)&Ps[(w * 64 + qi * 16 + l15) * 136 + db * 16 + quad * 4] = ll;
        }
    __syncthreads();
#pragma unroll
    for (int t = 0; t < 16; t++) {
        int c = t * 256 + tid;
        int row = c >> 4, col8 = (c & 15) << 3;
        *(u16x8*)&cl[obase + (size_t)row * HD + col8] = *(const u16x8*)&Ps[row * 136 + col8];
    }
}

// ==================== launch =================================================
extern "C" void kernel_launch(void* const* d_in, const int* in_sizes, int n_in,
                              void* d_out, int out_size, void* d_ws, size_t ws_size,
                              hipStream_t stream) {
    const float* X  = (const float*)d_in[0];
    const float* Wq = (const float*)d_in[1];
    const float* bq = (const float*)d_in[2];
    const float* Wk = (const float*)d_in[3];
    const float* bk = (const float*)d_in[4];
    const float* Wv = (const float*)d_in[5];
    const float* bv = (const float*)d_in[6];
    const float* Wo = (const float*)d_in[7];
    const float* bo = (const float*)d_in[8];
    float* out = (float*)d_out;

    const size_t QS = (size_t)NB * NH * SEQ * HD;   // 8,388,608 elems
    const size_t WS = (size_t)HIDDEN * HIDDEN;      // 4,194,304 elems
    float* q_ws = (float*)d_ws;
    float* k_ws = q_ws + QS;
    float* v_ws = k_ws + QS;
    float* cost = v_ws + QS;
    float* sint = cost + (size_t)SEQ * 64;
    ushort_t* Xh = (ushort_t*)(sint + (size_t)SEQ * 64);  // -> Qb after QKV
    ushort_t* Wh0 = Xh + QS;
    ushort_t* Wh1 = Wh0 + WS;
    ushort_t* Wh2 = Wh1 + WS;
    ushort_t* Woh = Wh2 + WS;
    ushort_t* Wol = Woh + WS;
    ushort_t* Kb  = Wol + WS;
    ushort_t* Vtb = Kb + QS;
    ushort_t* ctxh = (ushort_t*)q_ws;                     // blocked ctx over dead q_ws
    ushort_t* ctxl = ctxh + QS;

    k_rope_tables<<<(SEQ * 64) / 256, 256, 0, stream>>>(cost, sint);

    k_cvt_all<<<(XG + 3 * WG) / 256, 256, 0, stream>>>(
        (const float4*)X, (const float4*)Wq, (const float4*)Wk, (const float4*)Wv,
        (ushort4*)Xh, (ushort4*)Wh0, (ushort4*)Wh1, (ushort4*)Wh2);
    k_split<<<WS / 4 / 256, 256, 0, stream>>>((const float4*)Wo, (ushort4*)Woh, (ushort4*)Wol);

    k_gemm_qkv<<<dim3(32, 48), 256, 0, stream>>>(Xh, Wh0, Wh1, Wh2, bq, bk, bv,
                                                 q_ws, k_ws, v_ws);

    ushort_t* Qbb = Xh;   // X bf16 dead after QKV GEMM
    k_rope_pack<<<(NB * NH * SEQ * 64) / 256, 256, 0, stream>>>(q_ws, k_ws, cost, sint, Qbb, Kb);
    k_vpack<<<dim3(SEQ / 64, HD / 64, NB * NH), 256, 0, stream>>>(v_ws, Vtb);

    k_flash_mfma<<<256, 256, 0, stream>>>(Qbb, Kb, Vtb, ctxh, ctxl);

    k_gemm_o<<<dim3(32, 16), 256, 0, stream>>>(ctxh, ctxl, Woh, Wol, bo, out);
}

// Round 6
// 506.130 us; speedup vs baseline: 1.1836x; 1.1836x over previous
//
#include <hip/hip_runtime.h>
#include <hip/hip_bf16.h>
#include <math.h>

#define HIDDEN 2048
#define NH 16
#define HD 128
#define NB 2
#define SEQ 2048
#define K_DIM 2048

typedef unsigned int u32;
typedef unsigned short ushort_t;
typedef __bf16 bf16x8 __attribute__((ext_vector_type(8)));
typedef float f32x4 __attribute__((ext_vector_type(4)));
typedef ushort_t u16x8 __attribute__((ext_vector_type(8)));

// ---------- fp32 -> (bf16 hi, bf16 lo) split, RNE both halves ----------
__device__ __forceinline__ void split1(float x, unsigned short& h, unsigned short& l) {
    u32 u = __float_as_uint(x);
    u32 hr = (u + 0x7FFFu + ((u >> 16) & 1u)) >> 16;
    h = (unsigned short)hr;
    float r = x - __uint_as_float(hr << 16);
    u32 u2 = __float_as_uint(r);
    l = (unsigned short)((u2 + 0x7FFFu + ((u2 >> 16) & 1u)) >> 16);
}

__device__ __forceinline__ ushort_t bf16r(float x) {
    u32 u = __float_as_uint(x);
    return (ushort_t)((u + 0x7FFFu + ((u >> 16) & 1u)) >> 16);
}

__device__ __forceinline__ void gl_lds16(const void* g, void* l) {
    __builtin_amdgcn_global_load_lds(
        (const __attribute__((address_space(1))) u32*)g,
        (__attribute__((address_space(3))) u32*)l, 16, 0, 0);
}

// ==================== RoPE tables (double-precision trig) ====================
__global__ void k_rope_tables(float* __restrict__ ct, float* __restrict__ st) {
    int idx = blockIdx.x * 256 + threadIdx.x;   // exactly SEQ*64 threads
    int s = idx >> 6, d = idx & 63;
    double inv = pow(10000.0, -(double)d * (1.0 / 64.0));
    double ang = (double)s * inv;
    ct[idx] = (float)cos(ang);
    st[idx] = (float)sin(ang);
}

// ==================== fused fp32 -> bf16 (hi only) for X, Wq, Wk, Wv ========
#define XG 2097152   // X float4 groups
#define WG 1048576   // W float4 groups
__global__ void k_cvt_all(const float4* __restrict__ X, const float4* __restrict__ W0,
                          const float4* __restrict__ W1, const float4* __restrict__ W2,
                          ushort4* __restrict__ Xh, ushort4* __restrict__ H0,
                          ushort4* __restrict__ H1, ushort4* __restrict__ H2) {
    int idx = blockIdx.x * 256 + threadIdx.x;   // XG + 3*WG threads
    const float4* src;
    ushort4* dst;
    int off;
    if (idx < XG) { src = X; dst = Xh; off = idx; }
    else {
        int t = idx - XG;
        int m = t >> 20;        // WG = 2^20
        off = t & (WG - 1);
        src = (m == 0) ? W0 : (m == 1) ? W1 : W2;
        dst = (m == 0) ? H0 : (m == 1) ? H1 : H2;
    }
    float4 x = src[off];
    ushort4 h;
    h.x = bf16r(x.x); h.y = bf16r(x.y); h.z = bf16r(x.z); h.w = bf16r(x.w);
    dst[off] = h;
}

// ==================== fp32 -> bf16 hi/lo split (Wo only) =====================
__global__ void k_split(const float4* __restrict__ src, ushort4* __restrict__ hi,
                        ushort4* __restrict__ lo) {
    int idx = blockIdx.x * 256 + threadIdx.x;
    float4 x = src[idx];
    ushort4 h, l;
    split1(x.x, h.x, l.x);
    split1(x.y, h.y, l.y);
    split1(x.z, h.z, l.z);
    split1(x.w, h.w, l.w);
    hi[idx] = h;
    lo[idx] = l;
}

// ==================== fused QKV plain-bf16 MFMA GEMM =========================
__global__ __launch_bounds__(256)
void k_gemm_qkv(const ushort_t* __restrict__ Xh,
                const ushort_t* __restrict__ W0, const ushort_t* __restrict__ W1,
                const ushort_t* __restrict__ W2,
                const float* __restrict__ b0, const float* __restrict__ b1,
                const float* __restrict__ b2,
                float* __restrict__ o0, float* __restrict__ o1, float* __restrict__ o2) {
    __shared__ ushort_t As[128 * 32];
    __shared__ ushort_t Bs[128 * 32];
    const int tid = threadIdx.x;
    const int lane = tid & 63;
    const int w = tid >> 6;
    const int wm = w & 1, wn = w >> 1;
    const int quad = lane >> 4;
    const int l15 = lane & 15;
    const int m0 = blockIdx.x << 7;
    const int mat = blockIdx.y >> 4;
    const int n0 = (blockIdx.y & 15) << 7;
    const ushort_t* Wsel = (mat == 0) ? W0 : (mat == 1) ? W1 : W2;
    const float* bias = (mat == 0) ? b0 : (mat == 1) ? b1 : b2;
    float* out = (mat == 0) ? o0 : (mat == 1) ? o1 : o2;

    const ushort_t* src = (w < 2) ? Xh : Wsel;
    const int rbase = ((w < 2) ? m0 : n0) + (w & 1) * 64;
    ushort_t* lbase = ((w < 2) ? As : Bs) + (w & 1) * 64 * 32;
    const int lrow = lane >> 2;
    const int lk = (lane & 3) << 3;
    const ushort_t* gp[4];
    ushort_t* lp[4];
#pragma unroll
    for (int i = 0; i < 4; i++) {
        gp[i] = src + (size_t)(rbase + i * 16 + lrow) * K_DIM + lk;
        lp[i] = lbase + i * 512;
    }

    f32x4 acc[4][4];
#pragma unroll
    for (int i = 0; i < 4; i++)
#pragma unroll
        for (int j = 0; j < 4; j++) acc[i][j] = (f32x4){0.f, 0.f, 0.f, 0.f};

    const int aoff = (wm * 64 + l15) * 32 + quad * 8;
    const int boff = (wn * 64 + l15) * 32 + quad * 8;

#pragma unroll
    for (int i = 0; i < 4; i++) gl_lds16(gp[i], lp[i]);
    __syncthreads();
    bf16x8 ah[4], bh[4];
#pragma unroll
    for (int f = 0; f < 4; f++) {
        ah[f] = *(const bf16x8*)&As[aoff + f * 512];
        bh[f] = *(const bf16x8*)&Bs[boff + f * 512];
    }

    for (int kt = 32; kt <= K_DIM; kt += 32) {
        __syncthreads();
        if (kt < K_DIM) {
#pragma unroll
            for (int i = 0; i < 4; i++) gl_lds16(gp[i] + kt, lp[i]);
        }
#pragma unroll
        for (int fm = 0; fm < 4; fm++)
#pragma unroll
            for (int fn = 0; fn < 4; fn++)
                acc[fm][fn] = __builtin_amdgcn_mfma_f32_16x16x32_bf16(ah[fm], bh[fn], acc[fm][fn], 0, 0, 0);
        if (kt < K_DIM) {
            __syncthreads();
#pragma unroll
            for (int f = 0; f < 4; f++) {
                ah[f] = *(const bf16x8*)&As[aoff + f * 512];
                bh[f] = *(const bf16x8*)&Bs[boff + f * 512];
            }
        }
    }

    float bcolv[4];
#pragma unroll
    for (int fn = 0; fn < 4; fn++) bcolv[fn] = bias[n0 + wn * 64 + fn * 16 + l15];

    const int h = n0 >> 7;
    const int bb = m0 >> 11;
    const int sb = (m0 & (SEQ - 1)) + wm * 64 + quad * 4;
    const int d = wn * 64 + l15;
    float* obase = out + ((size_t)(bb * NH + h) * SEQ) * HD;
#pragma unroll
    for (int fm = 0; fm < 4; fm++)
#pragma unroll
        for (int fn = 0; fn < 4; fn++)
#pragma unroll
            for (int r = 0; r < 4; r++)
                obase[(size_t)(sb + fm * 16 + r) * HD + d + fn * 16] =
                    acc[fm][fn][r] + bcolv[fn];
}

// ==================== bf16x3 MFMA GEMM (O-projection) ========================
// A (ctx hi/lo) is in BLOCKED layout (B,NH,S,HD): k-offset within a row is
// (kt>>7)*SEQ*HD + (kt&127). B (Wo hi/lo) is row-major K-contiguous.
__global__ __launch_bounds__(256)
void k_gemm_o(const ushort_t* __restrict__ Ah, const ushort_t* __restrict__ Al,
              const ushort_t* __restrict__ Bh, const ushort_t* __restrict__ Bl,
              const float* __restrict__ bias, float* __restrict__ out) {
    __shared__ ushort_t lds[4][128 * 32];
    const int tid = threadIdx.x;
    const int lane = tid & 63;
    const int w = tid >> 6;
    const int wm = w & 1, wn = w >> 1;
    const int quad = lane >> 4;
    const int l15 = lane & 15;
    const int m0 = blockIdx.x << 7;
    const int n0 = blockIdx.y << 7;
    const bool isA = (w < 2);

    const ushort_t* src = (w == 0) ? Ah : (w == 1) ? Al : (w == 2) ? Bh : Bl;
    const int lrow = lane >> 2;
    const int lk = (lane & 3) << 3;
    const ushort_t* gp[8];
    ushort_t* lp[8];
#pragma unroll
    for (int i = 0; i < 8; i++) {
        if (isA) {
            int m = m0 + i * 16 + lrow;
            int bb = m >> 11, s = m & (SEQ - 1);
            gp[i] = src + ((size_t)bb * NH * SEQ + s) * HD + lk;
        } else {
            gp[i] = src + (size_t)(n0 + i * 16 + lrow) * K_DIM + lk;
        }
        lp[i] = &lds[w][i * 512];
    }

    f32x4 acc[4][4];
#pragma unroll
    for (int i = 0; i < 4; i++)
#pragma unroll
        for (int j = 0; j < 4; j++) acc[i][j] = (f32x4){0.f, 0.f, 0.f, 0.f};

    const int aoff = (wm * 64 + l15) * 32 + quad * 8;
    const int boff = (wn * 64 + l15) * 32 + quad * 8;

#pragma unroll
    for (int i = 0; i < 8; i++) gl_lds16(gp[i], lp[i]);
    __syncthreads();
    bf16x8 ah[4], al[4], bh[4], bl[4];
#pragma unroll
    for (int f = 0; f < 4; f++) {
        ah[f] = *(const bf16x8*)&lds[0][aoff + f * 512];
        al[f] = *(const bf16x8*)&lds[1][aoff + f * 512];
        bh[f] = *(const bf16x8*)&lds[2][boff + f * 512];
        bl[f] = *(const bf16x8*)&lds[3][boff + f * 512];
    }

    for (int kt = 32; kt <= K_DIM; kt += 32) {
        __syncthreads();
        if (kt < K_DIM) {
            const size_t koff = isA ? ((size_t)(kt >> 7) * (SEQ * HD) + (kt & 127)) : (size_t)kt;
#pragma unroll
            for (int i = 0; i < 8; i++) gl_lds16(gp[i] + koff, lp[i]);
        }
#pragma unroll
        for (int fm = 0; fm < 4; fm++)
#pragma unroll
            for (int fn = 0; fn < 4; fn++) {
                acc[fm][fn] = __builtin_amdgcn_mfma_f32_16x16x32_bf16(ah[fm], bh[fn], acc[fm][fn], 0, 0, 0);
                acc[fm][fn] = __builtin_amdgcn_mfma_f32_16x16x32_bf16(ah[fm], bl[fn], acc[fm][fn], 0, 0, 0);
                acc[fm][fn] = __builtin_amdgcn_mfma_f32_16x16x32_bf16(al[fm], bh[fn], acc[fm][fn], 0, 0, 0);
            }
        if (kt < K_DIM) {
            __syncthreads();
#pragma unroll
            for (int f = 0; f < 4; f++) {
                ah[f] = *(const bf16x8*)&lds[0][aoff + f * 512];
                al[f] = *(const bf16x8*)&lds[1][aoff + f * 512];
                bh[f] = *(const bf16x8*)&lds[2][boff + f * 512];
                bl[f] = *(const bf16x8*)&lds[3][boff + f * 512];
            }
        }
    }

    float bcolv[4];
#pragma unroll
    for (int fn = 0; fn < 4; fn++) bcolv[fn] = bias[n0 + wn * 64 + fn * 16 + l15];

    const int mb = m0 + wm * 64 + quad * 4;
    const int nb = n0 + wn * 64 + l15;
#pragma unroll
    for (int fm = 0; fm < 4; fm++)
#pragma unroll
        for (int fn = 0; fn < 4; fn++)
#pragma unroll
            for (int r = 0; r < 4; r++)
                out[(size_t)(mb + fm * 16 + r) * HIDDEN + nb + fn * 16] =
                    acc[fm][fn][r] + bcolv[fn];
}

// ==================== RoPE + pack to bf16 (Q scaled by 1/sqrt(HD)) ===========
__global__ void k_rope_pack(const float* __restrict__ q, const float* __restrict__ k,
                            const float* __restrict__ ct, const float* __restrict__ st,
                            ushort_t* __restrict__ Qb, ushort_t* __restrict__ Kb) {
    int idx = blockIdx.x * 256 + threadIdx.x;   // exactly NB*NH*SEQ*64 threads
    int d = idx & 63;
    int s = (idx >> 6) & (SEQ - 1);
    int bh = idx >> 17;
    size_t base = ((size_t)bh * SEQ + s) * HD;
    float c = ct[(s << 6) + d], sn = st[(s << 6) + d];
    const float scq = 0.08838834764831845f;
    float q0 = q[base + d], q1 = q[base + d + 64];
    Qb[base + d]      = bf16r((q0 * c - q1 * sn) * scq);
    Qb[base + d + 64] = bf16r((q1 * c + q0 * sn) * scq);
    float k0 = k[base + d], k1 = k[base + d + 64];
    Kb[base + d]      = bf16r(k0 * c - k1 * sn);
    Kb[base + d + 64] = bf16r(k1 * c + k0 * sn);
}

// ==================== V transpose + pack: (B,H,S,D) fp32 -> (B,H,D,S) bf16 ===
__global__ __launch_bounds__(256)
void k_vpack(const float* __restrict__ v, ushort_t* __restrict__ vt) {
    __shared__ float t[64][65];
    const int tid = threadIdx.x;
    const int bh = blockIdx.z;
    const int s0 = blockIdx.x << 6;
    const int d0 = blockIdx.y << 6;
    const float* src = v + ((size_t)bh * SEQ + s0) * HD + d0;
    const int rr = tid >> 4;
    const int cc = (tid & 15) << 2;
#pragma unroll
    for (int i = 0; i < 4; i++) {
        float4 x = *(const float4*)(src + (size_t)(i * 16 + rr) * HD + cc);
        t[i * 16 + rr][cc] = x.x;
        t[i * 16 + rr][cc + 1] = x.y;
        t[i * 16 + rr][cc + 2] = x.z;
        t[i * 16 + rr][cc + 3] = x.w;
    }
    __syncthreads();
    const int dr = tid >> 2;
    const int sc_ = (tid & 3) << 4;
    ushort_t* dst = vt + ((size_t)bh * HD + d0 + dr) * SEQ + s0 + sc_;
    u16x8 o0, o1;
#pragma unroll
    for (int u = 0; u < 8; u++) o0[u] = bf16r(t[sc_ + u][dr]);
#pragma unroll
    for (int u = 0; u < 8; u++) o1[u] = bf16r(t[sc_ + 8 + u][dr]);
    *(u16x8*)dst = o0;
    *(u16x8*)(dst + 8) = o1;
}

// ==================== MFMA flash attention v4 ================================
// R4 loop structure (128 q-rows/block, 4 waves x 32 rows, VGPR<=128, 2 blk/CU)
// + R5's verified wins: XCD swizzle (bh = idx&31 -> all 16 q-tiles of a head
// land on one XCD; K/V stay L2-resident: FETCH 183->40MB) and coalesced
// epilogue via LDS re-layout into BLOCKED (B,NH,S,HD) ctx (kills the 8x
// partial-line write amplification: WRITE 258->~40MB).
__global__ __launch_bounds__(256, 2)
void k_flash_mfma(const ushort_t* __restrict__ Qb, const ushort_t* __restrict__ Kb,
                  const ushort_t* __restrict__ Vt,
                  ushort_t* __restrict__ ch, ushort_t* __restrict__ cl) {
    __shared__ ushort_t KV[128 * 136];
    __shared__ ushort_t Ps[128 * 136];
    const int tid = threadIdx.x;
    const int lane = tid & 63;
    const int w = tid >> 6;
    const int quad = lane >> 4;
    const int l15 = lane & 15;
    const int bi = blockIdx.x;
    const int bh = bi & 31;              // XCD swizzle: bh%8 == XCD id
    const int qt = bi >> 5;              // 0..15 (128 q rows each)
    const ushort_t* Qg = Qb + ((size_t)bh * SEQ + ((size_t)qt << 7)) * HD;
    const ushort_t* Kg = Kb + (size_t)bh * SEQ * HD;
    const ushort_t* Vg = Vt + (size_t)bh * HD * SEQ;

    // persistent Q fragments (B-operand): rows w*32+qi*16+l15, k = ks*32+quad*8
    bf16x8 qf[2][4];
#pragma unroll
    for (int qi = 0; qi < 2; qi++)
#pragma unroll
        for (int ks = 0; ks < 4; ks++)
            qf[qi][ks] = *(const bf16x8*)(Qg + (size_t)(w * 32 + qi * 16 + l15) * HD + ks * 32 + quad * 8);

    const int sr = tid >> 4;            // staging row 0..15
    const int sc8 = (tid & 15) << 3;    // staging col (8 elems = 16B)

    // prefetch chunk 0 K and V^T into registers
    u16x8 Kreg[8], Vreg[8];
#pragma unroll
    for (int i = 0; i < 8; i++)
        Kreg[i] = *(const u16x8*)(Kg + (size_t)(i * 16 + sr) * HD + sc8);
#pragma unroll
    for (int i = 0; i < 8; i++)
        Vreg[i] = *(const u16x8*)(Vg + (size_t)(i * 16 + sr) * SEQ + sc8);

    f32x4 acc[2][8];
#pragma unroll
    for (int qi = 0; qi < 2; qi++)
#pragma unroll
        for (int d = 0; d < 8; d++) acc[qi][d] = (f32x4){0.f, 0.f, 0.f, 0.f};
    float lp[2] = {0.f, 0.f};

    for (int kt = 0; kt < SEQ; kt += 128) {
        const int np = kt + 128;
        __syncthreads();                // prev PV reads of KV done
#pragma unroll
        for (int i = 0; i < 8; i++)     // stage K_i; refill Kreg = K_{i+1}
            *(u16x8*)&KV[(i * 16 + sr) * 136 + sc8] = Kreg[i];
        if (np < SEQ) {
#pragma unroll
            for (int i = 0; i < 8; i++)
                Kreg[i] = *(const u16x8*)(Kg + (size_t)(np + i * 16 + sr) * HD + sc8);
        }
        __syncthreads();

        // ---- scores transposed: sc[qi][j] = K(16 rows) x Q(16 rows)^T ----
        f32x4 sc[2][8];
#pragma unroll
        for (int qi = 0; qi < 2; qi++)
#pragma unroll
            for (int j = 0; j < 8; j++) sc[qi][j] = (f32x4){0.f, 0.f, 0.f, 0.f};
#pragma unroll
        for (int ks = 0; ks < 4; ks++) {
#pragma unroll
            for (int jh = 0; jh < 2; jh++) {
                bf16x8 kf[4];
#pragma unroll
                for (int j = 0; j < 4; j++)
                    kf[j] = *(const bf16x8*)&KV[((jh * 4 + j) * 16 + l15) * 136 + ks * 32 + quad * 8];
#pragma unroll
                for (int qi = 0; qi < 2; qi++)
#pragma unroll
                    for (int j = 0; j < 4; j++)
                        sc[qi][jh * 4 + j] = __builtin_amdgcn_mfma_f32_16x16x32_bf16(
                            kf[j], qf[qi][ks], sc[qi][jh * 4 + j], 0, 0, 0);
            }
        }

        // ---- p = exp(score); accumulate l; write P (8B contiguous) ----
#pragma unroll
        for (int qi = 0; qi < 2; qi++) {
            const int prow = (w * 32 + qi * 16 + l15) * 136 + quad * 4;
#pragma unroll
            for (int j = 0; j < 8; j++) {
                float p0 = __expf(sc[qi][j][0]);
                float p1 = __expf(sc[qi][j][1]);
                float p2 = __expf(sc[qi][j][2]);
                float p3 = __expf(sc[qi][j][3]);
                lp[qi] += (p0 + p1) + (p2 + p3);
                __hip_bfloat162 lo2 = __float22bfloat162_rn({p0, p1});
                __hip_bfloat162 hi2 = __float22bfloat162_rn({p2, p3});
                uint2 pk = make_uint2(*(u32*)&lo2, *(u32*)&hi2);
                *(uint2*)&Ps[prow + j * 16] = pk;
            }
        }
        __syncthreads();                // kf reads done + Ps visible
#pragma unroll
        for (int i = 0; i < 8; i++)     // stage V_i; refill Vreg = V_{i+1}
            *(u16x8*)&KV[(i * 16 + sr) * 136 + sc8] = Vreg[i];
        if (np < SEQ) {
#pragma unroll
            for (int i = 0; i < 8; i++)
                Vreg[i] = *(const u16x8*)(Vg + (size_t)(i * 16 + sr) * SEQ + np + sc8);
        }
        __syncthreads();

        // ---- PV transposed: acc[qi][db] = V^T(16 d-rows) x P^T ----
#pragma unroll
        for (int ks = 0; ks < 4; ks++) {
            bf16x8 pf[2];
#pragma unroll
            for (int qi = 0; qi < 2; qi++)
                pf[qi] = *(const bf16x8*)&Ps[(w * 32 + qi * 16 + l15) * 136 + ks * 32 + quad * 8];
#pragma unroll
            for (int db = 0; db < 8; db++) {
                bf16x8 vf = *(const bf16x8*)&KV[(db * 16 + l15) * 136 + ks * 32 + quad * 8];
#pragma unroll
                for (int qi = 0; qi < 2; qi++)
                    acc[qi][db] = __builtin_amdgcn_mfma_f32_16x16x32_bf16(vf, pf[qi], acc[qi][db], 0, 0, 0);
            }
        }
    }

    // ---- epilogue: l-reduce, normalize, re-layout via Ps, coalesced store ----
    float inv[2];
#pragma unroll
    for (int qi = 0; qi < 2; qi++) {
        float l = lp[qi];
        l += __shfl_xor(l, 16);
        l += __shfl_xor(l, 32);
        inv[qi] = 1.0f / l;
    }
    const size_t obase = ((size_t)bh * SEQ + ((size_t)qt << 7)) * HD;

    __syncthreads();                    // final PV pf reads of Ps done
    // hi pass
#pragma unroll
    for (int qi = 0; qi < 2; qi++)
#pragma unroll
        for (int db = 0; db < 8; db++) {
            ushort4 hh;
            ushort_t dum;
            split1(acc[qi][db][0] * inv[qi], hh.x, dum);
            split1(acc[qi][db][1] * inv[qi], hh.y, dum);
            split1(acc[qi][db][2] * inv[qi], hh.z, dum);
            split1(acc[qi][db][3] * inv[qi], hh.w, dum);
            *(ushort4*)&Ps[(w * 32 + qi * 16 + l15) * 136 + db * 16 + quad * 4] = hh;
        }
    __syncthreads();
#pragma unroll
    for (int t = 0; t < 8; t++) {
        int c = t * 256 + tid;
        int row = c >> 4, col8 = (c & 15) << 3;
        *(u16x8*)&ch[obase + (size_t)row * HD + col8] = *(const u16x8*)&Ps[row * 136 + col8];
    }
    __syncthreads();
    // lo pass
#pragma unroll
    for (int qi = 0; qi < 2; qi++)
#pragma unroll
        for (int db = 0; db < 8; db++) {
            ushort4 ll;
            ushort_t dum;
            split1(acc[qi][db][0] * inv[qi], dum, ll.x);
            split1(acc[qi][db][1] * inv[qi], dum, ll.y);
            split1(acc[qi][db][2] * inv[qi], dum, ll.z);
            split1(acc[qi][db][3] * inv[qi], dum, ll.w);
            *(ushort4*)&Ps[(w * 32 + qi * 16 + l15) * 136 + db * 16 + quad * 4] = ll;
        }
    __syncthreads();
#pragma unroll
    for (int t = 0; t < 8; t++) {
        int c = t * 256 + tid;
        int row = c >> 4, col8 = (c & 15) << 3;
        *(u16x8*)&cl[obase + (size_t)row * HD + col8] = *(const u16x8*)&Ps[row * 136 + col8];
    }
}

// ==================== launch =================================================
extern "C" void kernel_launch(void* const* d_in, const int* in_sizes, int n_in,
                              void* d_out, int out_size, void* d_ws, size_t ws_size,
                              hipStream_t stream) {
    const float* X  = (const float*)d_in[0];
    const float* Wq = (const float*)d_in[1];
    const float* bq = (const float*)d_in[2];
    const float* Wk = (const float*)d_in[3];
    const float* bk = (const float*)d_in[4];
    const float* Wv = (const float*)d_in[5];
    const float* bv = (const float*)d_in[6];
    const float* Wo = (const float*)d_in[7];
    const float* bo = (const float*)d_in[8];
    float* out = (float*)d_out;

    const size_t QS = (size_t)NB * NH * SEQ * HD;   // 8,388,608 elems
    const size_t WS = (size_t)HIDDEN * HIDDEN;      // 4,194,304 elems
    float* q_ws = (float*)d_ws;
    float* k_ws = q_ws + QS;
    float* v_ws = k_ws + QS;
    float* cost = v_ws + QS;
    float* sint = cost + (size_t)SEQ * 64;
    ushort_t* Xh = (ushort_t*)(sint + (size_t)SEQ * 64);  // -> Qb after QKV
    ushort_t* Wh0 = Xh + QS;
    ushort_t* Wh1 = Wh0 + WS;
    ushort_t* Wh2 = Wh1 + WS;
    ushort_t* Woh = Wh2 + WS;
    ushort_t* Wol = Woh + WS;
    ushort_t* Kb  = Wol + WS;
    ushort_t* Vtb = Kb + QS;
    ushort_t* ctxh = (ushort_t*)q_ws;                     // blocked ctx over dead q_ws
    ushort_t* ctxl = ctxh + QS;

    k_rope_tables<<<(SEQ * 64) / 256, 256, 0, stream>>>(cost, sint);

    k_cvt_all<<<(XG + 3 * WG) / 256, 256, 0, stream>>>(
        (const float4*)X, (const float4*)Wq, (const float4*)Wk, (const float4*)Wv,
        (ushort4*)Xh, (ushort4*)Wh0, (ushort4*)Wh1, (ushort4*)Wh2);
    k_split<<<WS / 4 / 256, 256, 0, stream>>>((const float4*)Wo, (ushort4*)Woh, (ushort4*)Wol);

    k_gemm_qkv<<<dim3(32, 48), 256, 0, stream>>>(Xh, Wh0, Wh1, Wh2, bq, bk, bv,
                                                 q_ws, k_ws, v_ws);

    ushort_t* Qbb = Xh;   // X bf16 dead after QKV GEMM
    k_rope_pack<<<(NB * NH * SEQ * 64) / 256, 256, 0, stream>>>(q_ws, k_ws, cost, sint, Qbb, Kb);
    k_vpack<<<dim3(SEQ / 64, HD / 64, NB * NH), 256, 0, stream>>>(v_ws, Vtb);

    k_flash_mfma<<<512, 256, 0, stream>>>(Qbb, Kb, Vtb, ctxh, ctxl);

    k_gemm_o<<<dim3(32, 16), 256, 0, stream>>>(ctxh, ctxl, Woh, Wol, bo, out);
}